// Round 7
// baseline (21994.800 us; speedup 1.0000x reference)
//
#include <hip/hip_runtime.h>
#include <cstdint>
#include <cstddef>

using u64 = unsigned long long;
using i64 = long long;
using s8  = signed char;

#define DEVI __device__ __forceinline__

// ---------------------------------------------------------------- reductions
DEVI double waveRed(double v) {
    #pragma unroll
    for (int o = 32; o > 0; o >>= 1) v += __shfl_down(v, o, 64);
    return v;
}

// ---------------------------------------------------------------- conv0 (XLA:CPU-style f32)
// Single sequential f32 FMA chain over taps in (kh, kw, ci) order, ci innermost
// (Eigen/oneDNN NHWC im2col+GEMM pattern). Boundary taps (pad zeros) skipped —
// fma(0,w,acc)=acc exactly.
DEVI float conv0_val(const float* __restrict__ x, const float* __restrict__ w0,
                     int n, int co, int h, int w) {
    #pragma clang fp contract(off)
    const float* wp = w0 + co * 27;     // [co][ci][kh][kw]
    const float* xb = x + n * 3072;
    float acc = 0.0f;
    #pragma unroll
    for (int kh = 0; kh < 3; ++kh) {
        int ih = h + kh - 1;
        #pragma unroll
        for (int kw = 0; kw < 3; ++kw) {
            int iw = w + kw - 1;
            if ((unsigned)ih >= 32u || (unsigned)iw >= 32u) continue;
            #pragma unroll
            for (int ci = 0; ci < 3; ++ci) {
                acc = __builtin_fmaf(xb[ci * 1024 + ih * 32 + iw],
                                     wp[ci * 9 + kh * 3 + kw], acc);
            }
        }
    }
    return acc;
}

__global__ __launch_bounds__(256) void conv0_sums(const float* __restrict__ x,
                                                  const float* __restrict__ w0,
                                                  double* __restrict__ sum,
                                                  double* __restrict__ sumsq) {
    int co = blockIdx.y;
    int pos = blockIdx.x * 256 + threadIdx.x;   // 262144 positions
    int n = pos >> 10, hw = pos & 1023;
    double y = (double)conv0_val(x, w0, n, co, hw >> 5, hw & 31);
    double v = waveRed(y);
    double v2 = waveRed(y * y);
    __shared__ double s1[4], s2[4];
    int wv = threadIdx.x >> 6;
    if ((threadIdx.x & 63) == 0) { s1[wv] = v; s2[wv] = v2; }
    __syncthreads();
    if (threadIdx.x == 0) {
        atomicAdd(&sum[co],   s1[0] + s1[1] + s1[2] + s1[3]);
        atomicAdd(&sumsq[co], s2[0] + s2[1] + s2[2] + s2[3]);
    }
}

__global__ void finalize_c0(const double* __restrict__ sum, const double* __restrict__ sumsq,
                            const float* __restrict__ g, const float* __restrict__ b,
                            double* __restrict__ M, double* __restrict__ A,
                            double* __restrict__ BB) {
    int c = threadIdx.x;    // 128
    double m = sum[c] / 262144.0;
    double var = sumsq[c] / 262144.0 - m * m;
    M[c]  = m;
    A[c]  = (double)g[c] / sqrt(var + 1e-5);
    BB[c] = (double)b[c];
}

// sign(bn0) as int8 {-1,0,1}; act layout NHWC [n][h][w][c]
__global__ __launch_bounds__(256) void conv0_sign(const float* __restrict__ x,
                                                  const float* __restrict__ w0,
                                                  const double* __restrict__ M,
                                                  const double* __restrict__ A,
                                                  const double* __restrict__ BB,
                                                  s8* __restrict__ act) {
    int gid = blockIdx.x * 256 + threadIdx.x;
    int c = gid & 127;
    int pos = gid >> 7;
    int n = pos >> 10, hw = pos & 1023;
    double y = (double)conv0_val(x, w0, n, c, hw >> 5, hw & 31);
    double t = A[c] * (y - M[c]) + BB[c];
    act[gid] = t > 0.0 ? 1 : (t < 0.0 ? -1 : 0);
}

// ---------------------------------------------------------------- weight signs
// layout [k][co][ci], k = kh*3+kw; source w[co][ci][kh][kw]
__global__ __launch_bounds__(256) void pack_wsgn(const float* __restrict__ w,
                                                 s8* __restrict__ wsg, int Ci, int Co) {
    int gid = blockIdx.x * 256 + threadIdx.x;   // total = 9*Ci*Co, gid = (k*Co+co)*Ci+ci
    int ci = gid % Ci;
    int rest = gid / Ci;
    int co = rest % Co;
    int k = rest / Co;
    float v = w[(size_t)(co * Ci + ci) * 9 + k];
    wsg[gid] = v > 0.0f ? 1 : (v < 0.0f ? -1 : 0);
}

// ---------------------------------------------------------------- naive binary conv
template <int Ci, int CO, int HI, bool POOL>
__global__ __launch_bounds__(256) void bconv_naive(const s8* __restrict__ act,
                                                   const s8* __restrict__ wsgn,
                                                   short* __restrict__ dots) {
    constexpr int WI = HI;
    constexpr int HO = POOL ? HI / 2 : HI;
    constexpr int WO = HO;
    int gid = blockIdx.x * 256 + threadIdx.x;
    int co = gid % CO;
    int pos = gid / CO;
    int wo = pos % WO;
    int t = pos / WO;
    int ho = t % HO;
    int n = t / HO;

    int best = -(1 << 30);
    #pragma unroll
    for (int py = 0; py < (POOL ? 2 : 1); ++py) {
        #pragma unroll
        for (int px = 0; px < (POOL ? 2 : 1); ++px) {
            int hc = POOL ? ho * 2 + py : ho;
            int wc = POOL ? wo * 2 + px : wo;
            int acc = 0;
            #pragma unroll
            for (int kh = 0; kh < 3; ++kh) {
                int ih = hc + kh - 1;
                if ((unsigned)ih >= (unsigned)HI) continue;
                #pragma unroll
                for (int kw = 0; kw < 3; ++kw) {
                    int iw = wc + kw - 1;
                    if ((unsigned)iw >= (unsigned)WI) continue;
                    const int* ap = (const int*)(act + (size_t)((n * HI + ih) * WI + iw) * Ci);
                    const int* wp = (const int*)(wsgn + (size_t)((kh * 3 + kw) * CO + co) * Ci);
                    #pragma unroll 4
                    for (int j = 0; j < Ci / 4; ++j) {
                        int a = ap[j], w = wp[j];
                        acc += (int)(s8)(a)        * (int)(s8)(w)
                             + (int)(s8)(a >> 8)   * (int)(s8)(w >> 8)
                             + (int)(s8)(a >> 16)  * (int)(s8)(w >> 16)
                             + (a >> 24)           * (w >> 24);
                    }
                }
            }
            best = acc > best ? acc : best;
        }
    }
    dots[gid] = (short)best;
}

// ---------------------------------------------------------------- BN int stats (exact)
template <int CO>
__global__ void stats_naive(const short* __restrict__ xin, int P, i64* __restrict__ sums) {
    int c = threadIdx.x;             // blockDim = CO
    i64 s = 0, s2 = 0;
    for (int p = blockIdx.x; p < P; p += gridDim.x) {
        i64 v = xin[(size_t)p * CO + c];
        s += v;
        s2 += v * v;
    }
    atomicAdd((u64*)&sums[c], (u64)s);
    atomicAdd((u64*)&sums[CO + c], (u64)s2);
}

__global__ void finalize_bn(const i64* __restrict__ sums,
                            const float* __restrict__ g, const float* __restrict__ b,
                            int CO, double cnt, double* __restrict__ M,
                            double* __restrict__ A, double* __restrict__ BB) {
    int c = blockIdx.x * blockDim.x + threadIdx.x;
    if (c >= CO) return;
    double m = (double)sums[c] / cnt;
    double var = (double)sums[CO + c] / cnt - m * m;
    M[c]  = m;
    A[c]  = (double)g[c] / sqrt(var + 1e-5);
    BB[c] = (double)b[c];
}

// ---------------------------------------------------------------- sign(hardtanh(bn(x)))
template <int CO>
__global__ __launch_bounds__(256) void binsign_naive(const short* __restrict__ xin,
                                                     const double* __restrict__ M,
                                                     const double* __restrict__ A,
                                                     const double* __restrict__ BB,
                                                     s8* __restrict__ act) {
    int gid = blockIdx.x * 256 + threadIdx.x;   // gid = p*CO + c
    int c = gid % CO;
    double t = A[c] * ((double)xin[gid] - M[c]) + BB[c];
    act[gid] = t > 0.0 ? 1 : (t < 0.0 ? -1 : 0);
}

// ---------------------------------------------------------------- FC head
__global__ __launch_bounds__(256) void fc_naive(const short* __restrict__ x5,
                                                const double* __restrict__ M,
                                                const double* __restrict__ A,
                                                const double* __restrict__ BB,
                                                const float* __restrict__ wfc,
                                                const float* __restrict__ bfc,
                                                float* __restrict__ out) {
    int n = blockIdx.x / 10, k = blockIdx.x % 10;
    double acc = 0.0;
    for (int i = threadIdx.x; i < 8192; i += 256) {
        int c = i >> 4, hw = i & 15, h = hw >> 2, ww = hw & 3;
        double t = A[c] * ((double)x5[(size_t)((n * 4 + h) * 4 + ww) * 512 + c] - M[c]) + BB[c];
        t = t < -1.0 ? -1.0 : (t > 1.0 ? 1.0 : t);
        acc += t * (double)wfc[(size_t)k * 8192 + i];
    }
    acc = waveRed(acc);
    __shared__ double sd[4];
    if ((threadIdx.x & 63) == 0) sd[threadIdx.x >> 6] = acc;
    __syncthreads();
    if (threadIdx.x == 0)
        out[n * 10 + k] = (float)(sd[0] + sd[1] + sd[2] + sd[3] + (double)bfc[k]);
}

// ---------------------------------------------------------------- launch
extern "C" void kernel_launch(void* const* d_in, const int* in_sizes, int n_in,
                              void* d_out, int out_size, void* d_ws, size_t ws_size,
                              hipStream_t stream) {
    (void)in_sizes; (void)n_in; (void)out_size; (void)ws_size;

    const float* x   = (const float*)d_in[0];
    const float* w0  = (const float*)d_in[1];
    const float* g0  = (const float*)d_in[2];
    const float* b0  = (const float*)d_in[3];
    const float* w1  = (const float*)d_in[4];
    const float* g1  = (const float*)d_in[5];
    const float* b1  = (const float*)d_in[6];
    const float* w2  = (const float*)d_in[7];
    const float* g2  = (const float*)d_in[8];
    const float* b2  = (const float*)d_in[9];
    const float* w3  = (const float*)d_in[10];
    const float* g3  = (const float*)d_in[11];
    const float* b3  = (const float*)d_in[12];
    const float* w4  = (const float*)d_in[13];
    const float* g4  = (const float*)d_in[14];
    const float* b4  = (const float*)d_in[15];
    const float* w5  = (const float*)d_in[16];
    const float* g5  = (const float*)d_in[17];
    const float* b5  = (const float*)d_in[18];
    const float* wfc = (const float*)d_in[19];
    const float* bfc = (const float*)d_in[20];
    float* out = (float*)d_out;

    // ---- workspace layout (~76.5 MB) ----
    char* ws = (char*)d_ws;
    double* sum0   = (double*)ws;                  // 128
    double* sumsq0 = sum0 + 128;                   // 128
    i64* isums = (i64*)(sumsq0 + 128);             // 5 layers * 1024
    double* M  = (double*)(ws + 65536);            // 6*512
    double* A  = M + 3072;
    double* BB = A + 3072;
    s8* wsg1 = (s8*)(ws + 65536 + 73728);
    s8* wsg2 = wsg1 + 147456;
    s8* wsg3 = wsg2 + 294912;
    s8* wsg4 = wsg3 + 589824;
    s8* wsg5 = wsg4 + 1179648;
    s8* actR1 = wsg5 + 2359296;                    // 33.55 MB region (act0/act2/act4)
    s8* actR2 = actR1 + 33554432;                  // 8.39 MB region (act1/act3)
    short* dots = (short*)(actR2 + 8388608);       // 33.55 MB max (L2)

    hipMemsetAsync(d_ws, 0, 43008, stream);

    // weight signs
    pack_wsgn<<<576,  256, 0, stream>>>(w1, wsg1, 128, 128);
    pack_wsgn<<<1152, 256, 0, stream>>>(w2, wsg2, 128, 256);
    pack_wsgn<<<2304, 256, 0, stream>>>(w3, wsg3, 256, 256);
    pack_wsgn<<<4608, 256, 0, stream>>>(w4, wsg4, 256, 512);
    pack_wsgn<<<9216, 256, 0, stream>>>(w5, wsg5, 512, 512);

    // conv0 (f32 FMA, (kh,kw,ci) order) + BN0 + sign
    conv0_sums<<<dim3(1024, 128), 256, 0, stream>>>(x, w0, sum0, sumsq0);
    finalize_c0<<<1, 128, 0, stream>>>(sum0, sumsq0, g0, b0, M, A, BB);
    conv0_sign<<<131072, 256, 0, stream>>>(x, w0, M, A, BB, actR1);

    // L1: 128->128 @32x32, pool -> 16x16
    bconv_naive<128, 128, 32, true><<<32768, 256, 0, stream>>>(actR1, wsg1, dots);
    stats_naive<128><<<256, 128, 0, stream>>>(dots, 65536, isums);
    finalize_bn<<<1, 128, 0, stream>>>(isums, g1, b1, 128, 65536.0, M + 512, A + 512, BB + 512);
    binsign_naive<128><<<32768, 256, 0, stream>>>(dots, M + 512, A + 512, BB + 512, actR2);

    // L2: 128->256 @16x16
    bconv_naive<128, 256, 16, false><<<65536, 256, 0, stream>>>(actR2, wsg2, dots);
    stats_naive<256><<<256, 256, 0, stream>>>(dots, 65536, isums + 1024);
    finalize_bn<<<1, 256, 0, stream>>>(isums + 1024, g2, b2, 256, 65536.0, M + 1024, A + 1024, BB + 1024);
    binsign_naive<256><<<65536, 256, 0, stream>>>(dots, M + 1024, A + 1024, BB + 1024, actR1);

    // L3: 256->256 @16x16, pool -> 8x8
    bconv_naive<256, 256, 16, true><<<16384, 256, 0, stream>>>(actR1, wsg3, dots);
    stats_naive<256><<<256, 256, 0, stream>>>(dots, 16384, isums + 2048);
    finalize_bn<<<1, 256, 0, stream>>>(isums + 2048, g3, b3, 256, 16384.0, M + 1536, A + 1536, BB + 1536);
    binsign_naive<256><<<16384, 256, 0, stream>>>(dots, M + 1536, A + 1536, BB + 1536, actR2);

    // L4: 256->512 @8x8
    bconv_naive<256, 512, 8, false><<<32768, 256, 0, stream>>>(actR2, wsg4, dots);
    stats_naive<512><<<256, 512, 0, stream>>>(dots, 16384, isums + 3072);
    finalize_bn<<<1, 512, 0, stream>>>(isums + 3072, g4, b4, 512, 16384.0, M + 2048, A + 2048, BB + 2048);
    binsign_naive<512><<<32768, 256, 0, stream>>>(dots, M + 2048, A + 2048, BB + 2048, actR1);

    // L5: 512->512 @8x8, pool -> 4x4
    bconv_naive<512, 512, 8, true><<<8192, 256, 0, stream>>>(actR1, wsg5, dots);
    stats_naive<512><<<256, 512, 0, stream>>>(dots, 4096, isums + 4096);
    finalize_bn<<<1, 512, 0, stream>>>(isums + 4096, g5, b5, 512, 4096.0, M + 2560, A + 2560, BB + 2560);

    // FC head
    fc_naive<<<2560, 256, 0, stream>>>(dots, M + 2560, A + 2560, BB + 2560, wfc, bfc, out);
}

// Round 8
// 2856.626 us; speedup vs baseline: 7.6996x; 7.6996x over previous
//
#include <hip/hip_runtime.h>
#include <cstdint>
#include <cstddef>

using u64 = unsigned long long;
using i64 = long long;

#define DEVI __device__ __forceinline__

// ---------------------------------------------------------------- reductions
DEVI double waveRed(double v) {
    #pragma unroll
    for (int o = 32; o > 0; o >>= 1) v += __shfl_down(v, o, 64);
    return v;
}

// ---------------------------------------------------------------- conv0 (np-f32: FMA chain, (kh,kw,ci) order)
DEVI float conv0_val(const float* __restrict__ x, const float* __restrict__ wp27,
                     int n, int h, int w) {
    #pragma clang fp contract(off)
    const float* xb = x + n * 3072;
    float acc = 0.0f;
    #pragma unroll
    for (int kh = 0; kh < 3; ++kh) {
        int ih = h + kh - 1;
        #pragma unroll
        for (int kw = 0; kw < 3; ++kw) {
            int iw = w + kw - 1;
            if ((unsigned)ih >= 32u || (unsigned)iw >= 32u) continue;
            #pragma unroll
            for (int ci = 0; ci < 3; ++ci) {
                acc = __builtin_fmaf(xb[ci * 1024 + ih * 32 + iw],
                                     wp27[ci * 9 + kh * 3 + kw], acc);
            }
        }
    }
    return acc;
}

// Pass A: per-channel f64 sum/sumsq of the f32 conv0 values. co = blockIdx.y
// (weight reads are wave-uniform -> scalar path, no scatter).
__global__ __launch_bounds__(256) void conv0_sums(const float* __restrict__ x,
                                                  const float* __restrict__ w0,
                                                  double* __restrict__ sum,
                                                  double* __restrict__ sumsq) {
    int co = blockIdx.y;
    int pos = blockIdx.x * 256 + threadIdx.x;   // 262144 positions
    int n = pos >> 10, hw = pos & 1023;
    double y = (double)conv0_val(x, w0 + co * 27, n, hw >> 5, hw & 31);
    double v = waveRed(y);
    double v2 = waveRed(y * y);
    __shared__ double s1[4], s2[4];
    int wv = threadIdx.x >> 6;
    if ((threadIdx.x & 63) == 0) { s1[wv] = v; s2[wv] = v2; }
    __syncthreads();
    if (threadIdx.x == 0) {
        atomicAdd(&sum[co],   s1[0] + s1[1] + s1[2] + s1[3]);
        atomicAdd(&sumsq[co], s2[0] + s2[1] + s2[2] + s2[3]);
    }
}

__global__ void finalize_c0(const double* __restrict__ sum, const double* __restrict__ sumsq,
                            const float* __restrict__ g, const float* __restrict__ b,
                            double* __restrict__ M, double* __restrict__ A,
                            double* __restrict__ BB) {
    int c = threadIdx.x;    // 128
    double m = sum[c] / 262144.0;
    double var = sumsq[c] / 262144.0 - m * m;
    M[c]  = m;
    A[c]  = (double)g[c] / sqrt(var + 1e-5);
    BB[c] = (double)b[c];
}

// Pass B: recompute conv0 (identical f32 arithmetic, weights from LDS to kill
// the per-lane 64-line scatter), binarize, ballot-pack into channel bitplanes.
// A0: [pos][2] u64, bit i of word w = (channel w*64+i) sign.
__global__ __launch_bounds__(256) void conv0_pack(const float* __restrict__ x,
                                                  const float* __restrict__ w0,
                                                  const double* __restrict__ M,
                                                  const double* __restrict__ A,
                                                  const double* __restrict__ BB,
                                                  u64* __restrict__ A0) {
    __shared__ float wsh[3456];                 // 128 co * 27
    for (int i = threadIdx.x; i < 3456; i += 256) wsh[i] = w0[i];
    __syncthreads();
    int tid = threadIdx.x;
    int co = tid & 127;
    int p = (blockIdx.x << 1) | (tid >> 7);     // 2 positions per block
    int n = p >> 10, hw = p & 1023;
    float y = conv0_val(x, wsh + co * 27, n, hw >> 5, hw & 31);
    double t = A[co] * ((double)y - M[co]) + BB[co];
    u64 m = __ballot(t > 0.0);
    if ((tid & 63) == 0) A0[(size_t)p * 2 + ((tid >> 6) & 1)] = m;
}

// ---------------------------------------------------------------- weight bit-pack
// Wb layout: [k][cw][co], bit i of word = sign(w[co][cw*64+i][kh][kw]) > 0
__global__ __launch_bounds__(256) void pack_w(const float* __restrict__ w,
                                              u64* __restrict__ Wb, int Ci, int Co) {
    int widx = blockIdx.x * 4 + (threadIdx.x >> 6);
    int lane = threadIdx.x & 63;
    int CW = Ci >> 6;
    int co = widx % Co;
    int rest = widx / Co;
    int cw = rest % CW;
    int k = rest / CW;
    int kh = k / 3, kw = k % 3;
    int ci = (cw << 6) | lane;
    float v = w[((size_t)(co * Ci + ci) * 3 + kh) * 3 + kw];
    u64 m = __ballot(v > 0.0f);
    if (lane == 0) Wb[widx] = m;
}

// ---------------------------------------------------------------- bit binary conv
// A: [N][HI][WI][CW] packed; Wb: [9][CW][CO]; dots: NHWC int16 (pooled if POOL).
// dot = validBits - 2*popc(xor). Lanes = consecutive co -> A broadcast, Wb coalesced.
template <int CW, int CO, int HI, bool POOL>
__global__ __launch_bounds__(256) void bconv_bits(const u64* __restrict__ A,
                                                  const u64* __restrict__ Wb,
                                                  short* __restrict__ dots) {
    constexpr int WI = HI;
    constexpr int HO = POOL ? HI / 2 : HI;
    constexpr int WO = HO;
    int gid = blockIdx.x * 256 + threadIdx.x;
    int co = gid % CO;
    int pos = gid / CO;
    int wo = pos % WO;
    int t = pos / WO;
    int ho = t % HO;
    int n = t / HO;

    int best = -(1 << 30);
    #pragma unroll
    for (int py = 0; py < (POOL ? 2 : 1); ++py) {
        #pragma unroll
        for (int px = 0; px < (POOL ? 2 : 1); ++px) {
            int hc = POOL ? ho * 2 + py : ho;
            int wc = POOL ? wo * 2 + px : wo;
            int pc = 0, nv = 0;
            #pragma unroll
            for (int kh = 0; kh < 3; ++kh) {
                int ih = hc + kh - 1;
                if ((unsigned)ih >= (unsigned)HI) continue;
                #pragma unroll
                for (int kw = 0; kw < 3; ++kw) {
                    int iw = wc + kw - 1;
                    if ((unsigned)iw >= (unsigned)WI) continue;
                    const u64* ap = A + (size_t)((n * HI + ih) * WI + iw) * CW;
                    const u64* wp = Wb + (size_t)((kh * 3 + kw) * CW) * CO + co;
                    #pragma unroll
                    for (int cw = 0; cw < CW; ++cw)
                        pc += __popcll(ap[cw] ^ wp[(size_t)cw * CO]);
                    nv += CW * 64;
                }
            }
            int dot = nv - 2 * pc;
            best = dot > best ? dot : best;
        }
    }
    dots[gid] = (short)best;
}

// ---------------------------------------------------------------- BN int stats (exact)
template <int CO>
__global__ void stats_k(const short* __restrict__ xin, int P, i64* __restrict__ sums) {
    int c = threadIdx.x;             // blockDim = CO
    i64 s = 0, s2 = 0;
    for (int p = blockIdx.x; p < P; p += gridDim.x) {
        i64 v = xin[(size_t)p * CO + c];
        s += v;
        s2 += v * v;
    }
    atomicAdd((u64*)&sums[c], (u64)s);
    atomicAdd((u64*)&sums[CO + c], (u64)s2);
}

__global__ void finalize_bn(const i64* __restrict__ sums,
                            const float* __restrict__ g, const float* __restrict__ b,
                            int CO, double cnt, double* __restrict__ M,
                            double* __restrict__ A, double* __restrict__ BB) {
    int c = blockIdx.x * blockDim.x + threadIdx.x;
    if (c >= CO) return;
    double m = (double)sums[c] / cnt;
    double var = (double)sums[CO + c] / cnt - m * m;
    M[c]  = m;
    A[c]  = (double)g[c] / sqrt(var + 1e-5);
    BB[c] = (double)b[c];
}

// ---------------------------------------------------------------- binarize + bit-pack
template <int CO>
__global__ __launch_bounds__(256) void binpack_k(const short* __restrict__ xin,
                                                 const double* __restrict__ M,
                                                 const double* __restrict__ A,
                                                 const double* __restrict__ BB,
                                                 u64* __restrict__ Ab) {
    constexpr int CWo = CO / 64;
    int widx = blockIdx.x * 4 + (threadIdx.x >> 6);
    int lane = threadIdx.x & 63;
    int w = widx & (CWo - 1);
    int p = widx / CWo;
    int c = (w << 6) | lane;
    double t = A[c] * ((double)xin[(size_t)p * CO + c] - M[c]) + BB[c];
    u64 m = __ballot(t > 0.0);
    if (lane == 0) Ab[widx] = m;
}

// ---------------------------------------------------------------- FC head
__global__ __launch_bounds__(256) void fc_k(const short* __restrict__ x5,
                                            const double* __restrict__ M,
                                            const double* __restrict__ A,
                                            const double* __restrict__ BB,
                                            const float* __restrict__ wfc,
                                            const float* __restrict__ bfc,
                                            float* __restrict__ out) {
    int n = blockIdx.x / 10, k = blockIdx.x % 10;
    double acc = 0.0;
    for (int i = threadIdx.x; i < 8192; i += 256) {
        int c = i >> 4, hw = i & 15, h = hw >> 2, ww = hw & 3;
        double t = A[c] * ((double)x5[(size_t)((n * 4 + h) * 4 + ww) * 512 + c] - M[c]) + BB[c];
        t = t < -1.0 ? -1.0 : (t > 1.0 ? 1.0 : t);
        acc += t * (double)wfc[(size_t)k * 8192 + i];
    }
    acc = waveRed(acc);
    __shared__ double sd[4];
    if ((threadIdx.x & 63) == 0) sd[threadIdx.x >> 6] = acc;
    __syncthreads();
    if (threadIdx.x == 0)
        out[n * 10 + k] = (float)(sd[0] + sd[1] + sd[2] + sd[3] + (double)bfc[k]);
}

// ---------------------------------------------------------------- launch
extern "C" void kernel_launch(void* const* d_in, const int* in_sizes, int n_in,
                              void* d_out, int out_size, void* d_ws, size_t ws_size,
                              hipStream_t stream) {
    (void)in_sizes; (void)n_in; (void)out_size; (void)ws_size;

    const float* x   = (const float*)d_in[0];
    const float* w0  = (const float*)d_in[1];
    const float* g0  = (const float*)d_in[2];
    const float* b0  = (const float*)d_in[3];
    const float* w1  = (const float*)d_in[4];
    const float* g1  = (const float*)d_in[5];
    const float* b1  = (const float*)d_in[6];
    const float* w2  = (const float*)d_in[7];
    const float* g2  = (const float*)d_in[8];
    const float* b2  = (const float*)d_in[9];
    const float* w3  = (const float*)d_in[10];
    const float* g3  = (const float*)d_in[11];
    const float* b3  = (const float*)d_in[12];
    const float* w4  = (const float*)d_in[13];
    const float* g4  = (const float*)d_in[14];
    const float* b4  = (const float*)d_in[15];
    const float* w5  = (const float*)d_in[16];
    const float* g5  = (const float*)d_in[17];
    const float* b5  = (const float*)d_in[18];
    const float* wfc = (const float*)d_in[19];
    const float* bfc = (const float*)d_in[20];
    float* out = (float*)d_out;

    // ---- workspace layout (~43.2 MB) ----
    char* ws = (char*)d_ws;
    double* sum0   = (double*)ws;                  // 128
    double* sumsq0 = sum0 + 128;                   // 128
    i64* isums = (i64*)(sumsq0 + 128);             // 5 layers * 1024
    // zero span: 2048 + 40960 = 43008 bytes
    double* M  = (double*)(ws + 65536);            // 6*512
    double* A  = M + 3072;
    double* BB = A + 3072;
    char* p = ws + 65536 + 73728;
    u64* A0 = (u64*)p;  p += (size_t)262144 * 2 * 8;   // 4 MiB
    u64* A1 = (u64*)p;  p += (size_t)65536 * 2 * 8;    // 1 MiB
    u64* A2 = (u64*)p;  p += (size_t)65536 * 4 * 8;    // 2 MiB
    u64* A3 = (u64*)p;  p += (size_t)16384 * 4 * 8;    // 0.5 MiB
    u64* A4 = (u64*)p;  p += (size_t)16384 * 8 * 8;    // 1 MiB
    u64* Wb1 = (u64*)p; p += 2304 * 8;
    u64* Wb2 = (u64*)p; p += 4608 * 8;
    u64* Wb3 = (u64*)p; p += 9216 * 8;
    u64* Wb4 = (u64*)p; p += 18432 * 8;
    u64* Wb5 = (u64*)p; p += 36864 * 8;
    p = (char*)(((uintptr_t)p + 255) & ~(uintptr_t)255);
    short* dots = (short*)p;                       // max 65536*256*2 = 33.5 MB

    hipMemsetAsync(d_ws, 0, 43008, stream);

    // weight bit-packs
    pack_w<<<576,  256, 0, stream>>>(w1, Wb1, 128, 128);
    pack_w<<<1152, 256, 0, stream>>>(w2, Wb2, 128, 256);
    pack_w<<<2304, 256, 0, stream>>>(w3, Wb3, 256, 256);
    pack_w<<<4608, 256, 0, stream>>>(w4, Wb4, 256, 512);
    pack_w<<<9216, 256, 0, stream>>>(w5, Wb5, 512, 512);

    // conv0 (np-f32 FMA (kh,kw,ci)) + BN0 + ballot pack
    conv0_sums<<<dim3(1024, 128), 256, 0, stream>>>(x, w0, sum0, sumsq0);
    finalize_c0<<<1, 128, 0, stream>>>(sum0, sumsq0, g0, b0, M, A, BB);
    conv0_pack<<<131072, 256, 0, stream>>>(x, w0, M, A, BB, A0);

    // L1: 128->128 @32x32, pool -> 16x16
    bconv_bits<2, 128, 32, true><<<32768, 256, 0, stream>>>(A0, Wb1, dots);
    stats_k<128><<<256, 128, 0, stream>>>(dots, 65536, isums);
    finalize_bn<<<1, 128, 0, stream>>>(isums, g1, b1, 128, 65536.0, M + 512, A + 512, BB + 512);
    binpack_k<128><<<32768, 256, 0, stream>>>(dots, M + 512, A + 512, BB + 512, A1);

    // L2: 128->256 @16x16
    bconv_bits<2, 256, 16, false><<<65536, 256, 0, stream>>>(A1, Wb2, dots);
    stats_k<256><<<256, 256, 0, stream>>>(dots, 65536, isums + 1024);
    finalize_bn<<<1, 256, 0, stream>>>(isums + 1024, g2, b2, 256, 65536.0, M + 1024, A + 1024, BB + 1024);
    binpack_k<256><<<65536, 256, 0, stream>>>(dots, M + 1024, A + 1024, BB + 1024, A2);

    // L3: 256->256 @16x16, pool -> 8x8
    bconv_bits<4, 256, 16, true><<<16384, 256, 0, stream>>>(A2, Wb3, dots);
    stats_k<256><<<256, 256, 0, stream>>>(dots, 16384, isums + 2048);
    finalize_bn<<<1, 256, 0, stream>>>(isums + 2048, g3, b3, 256, 16384.0, M + 1536, A + 1536, BB + 1536);
    binpack_k<256><<<16384, 256, 0, stream>>>(dots, M + 1536, A + 1536, BB + 1536, A3);

    // L4: 256->512 @8x8
    bconv_bits<4, 512, 8, false><<<32768, 256, 0, stream>>>(A3, Wb4, dots);
    stats_k<512><<<256, 512, 0, stream>>>(dots, 16384, isums + 3072);
    finalize_bn<<<1, 512, 0, stream>>>(isums + 3072, g4, b4, 512, 16384.0, M + 2048, A + 2048, BB + 2048);
    binpack_k<512><<<32768, 256, 0, stream>>>(dots, M + 2048, A + 2048, BB + 2048, A4);

    // L5: 512->512 @8x8, pool -> 4x4
    bconv_bits<8, 512, 8, true><<<8192, 256, 0, stream>>>(A4, Wb5, dots);
    stats_k<512><<<256, 512, 0, stream>>>(dots, 4096, isums + 4096);
    finalize_bn<<<1, 512, 0, stream>>>(isums + 4096, g5, b5, 512, 4096.0, M + 2560, A + 2560, BB + 2560);

    // FC head
    fc_k<<<2560, 256, 0, stream>>>(dots, M + 2560, A + 2560, BB + 2560, wfc, bfc, out);
}

// Round 10
// 1260.177 us; speedup vs baseline: 17.4537x; 2.2668x over previous
//
#include <hip/hip_runtime.h>
#include <cstdint>
#include <cstddef>

using u64 = unsigned long long;
using i64 = long long;

#define DEVI __device__ __forceinline__

// ---------------------------------------------------------------- reductions
DEVI double waveRed(double v) {
    #pragma unroll
    for (int o = 32; o > 0; o >>= 1) v += __shfl_down(v, o, 64);
    return v;
}

// ---------------------------------------------------------------- conv0 stats (np-f32: FMA chain, (kh,kw,ci) order)
// One block per image. x + w staged in LDS; weights reordered TAP-MAJOR so
// wsh[co*27 + (kh*3+kw)*3 + ci] pairs with xv[j] (same tap order). Chain runs
// j=0..26 == (kh,kw,ci) order -> bit-identical to the verified R7 arithmetic.
// Boundary taps are exact zeros: fma(0,w,acc)==acc.
__global__ __launch_bounds__(256, 1) void conv0_sums2(const float* __restrict__ x,
                                                      const float* __restrict__ w0,
                                                      double* __restrict__ sum,
                                                      double* __restrict__ sumsq) {
    __shared__ float xs[3072];
    __shared__ float wsh[3456];
    __shared__ double redS[4][128], redS2[4][128];
    int tid = threadIdx.x, n = blockIdx.x;
    for (int i = tid; i < 3072; i += 256) xs[i] = x[n * 3072 + i];
    for (int i = tid; i < 3456; i += 256) {
        int co = i / 27, j = i % 27;       // j = tap-major (kh*3+kw)*3 + ci
        int ci = j % 3, k = j / 3;
        wsh[i] = w0[co * 27 + ci * 9 + k];
    }
    __syncthreads();

    float xv[4][27];
    #pragma unroll
    for (int k = 0; k < 4; ++k) {
        int pos = tid + k * 256, h = pos >> 5, w = pos & 31;
        #pragma unroll
        for (int kh = 0; kh < 3; ++kh) {
            #pragma unroll
            for (int kw = 0; kw < 3; ++kw) {
                #pragma unroll
                for (int ci = 0; ci < 3; ++ci) {
                    int ih = h + kh - 1, iw = w + kw - 1;
                    bool ok = (unsigned)ih < 32u && (unsigned)iw < 32u;
                    xv[k][(kh * 3 + kw) * 3 + ci] = ok ? xs[ci * 1024 + ih * 32 + iw] : 0.0f;
                }
            }
        }
    }
    int lane = tid & 63, wv = tid >> 6;
    for (int co = 0; co < 128; ++co) {
        #pragma clang fp contract(off)
        const float* wp = &wsh[co * 27];
        float a0 = 0.f, a1 = 0.f, a2 = 0.f, a3 = 0.f;
        #pragma unroll
        for (int j = 0; j < 27; ++j) {
            float wj = wp[j];
            a0 = __builtin_fmaf(xv[0][j], wj, a0);
            a1 = __builtin_fmaf(xv[1][j], wj, a1);
            a2 = __builtin_fmaf(xv[2][j], wj, a2);
            a3 = __builtin_fmaf(xv[3][j], wj, a3);
        }
        double y0 = a0, y1 = a1, y2 = a2, y3 = a3;
        double s  = (y0 + y1) + (y2 + y3);
        double s2 = (y0 * y0 + y1 * y1) + (y2 * y2 + y3 * y3);
        s = waveRed(s); s2 = waveRed(s2);
        if (lane == 0) { redS[wv][co] = s; redS2[wv][co] = s2; }
    }
    __syncthreads();
    if (tid < 128) {
        atomicAdd(&sum[tid], (redS[0][tid] + redS[1][tid]) + (redS[2][tid] + redS[3][tid]));
    } else {
        int c = tid - 128;
        atomicAdd(&sumsq[c], (redS2[0][c] + redS2[1][c]) + (redS2[2][c] + redS2[3][c]));
    }
}

__global__ void finalize_c0(const double* __restrict__ sum, const double* __restrict__ sumsq,
                            const float* __restrict__ g, const float* __restrict__ b,
                            double* __restrict__ M, double* __restrict__ A,
                            double* __restrict__ BB) {
    int c = threadIdx.x;    // 128
    double m = sum[c] / 262144.0;
    double var = sumsq[c] / 262144.0 - m * m;
    M[c]  = m;
    A[c]  = (double)g[c] / sqrt(var + 1e-5);
    BB[c] = (double)b[c];
}

// ---------------------------------------------------------------- conv0 pack
// One block per image; per-thread co-loop builds the 2 u64 bitplane words.
// Same tap-major weight staging as conv0_sums2.
__global__ __launch_bounds__(256, 1) void conv0_pack2(const float* __restrict__ x,
                                                      const float* __restrict__ w0,
                                                      const double* __restrict__ M,
                                                      const double* __restrict__ A,
                                                      const double* __restrict__ BB,
                                                      u64* __restrict__ A0) {
    __shared__ float xs[3072];
    __shared__ float wsh[3456];
    __shared__ double msh[128], ash[128], bsh[128];
    int tid = threadIdx.x, n = blockIdx.x;
    for (int i = tid; i < 3072; i += 256) xs[i] = x[n * 3072 + i];
    for (int i = tid; i < 3456; i += 256) {
        int co = i / 27, j = i % 27;       // j = tap-major (kh*3+kw)*3 + ci
        int ci = j % 3, k = j / 3;
        wsh[i] = w0[co * 27 + ci * 9 + k];
    }
    if (tid < 128) { msh[tid] = M[tid]; ash[tid] = A[tid]; bsh[tid] = BB[tid]; }
    __syncthreads();

    for (int k = 0; k < 4; ++k) {
        int pos = tid + k * 256, h = pos >> 5, w = pos & 31;
        float xv[27];
        #pragma unroll
        for (int kh = 0; kh < 3; ++kh) {
            #pragma unroll
            for (int kw = 0; kw < 3; ++kw) {
                #pragma unroll
                for (int ci = 0; ci < 3; ++ci) {
                    int ih = h + kh - 1, iw = w + kw - 1;
                    bool ok = (unsigned)ih < 32u && (unsigned)iw < 32u;
                    xv[(kh * 3 + kw) * 3 + ci] = ok ? xs[ci * 1024 + ih * 32 + iw] : 0.0f;
                }
            }
        }
        u64 b0 = 0, b1 = 0;
        #pragma unroll 4
        for (int co = 0; co < 128; ++co) {
            #pragma clang fp contract(off)
            float acc = 0.f;
            const float* wp = &wsh[co * 27];
            #pragma unroll
            for (int j = 0; j < 27; ++j) acc = __builtin_fmaf(xv[j], wp[j], acc);
            double t = ash[co] * ((double)acc - msh[co]) + bsh[co];
            u64 bit = t > 0.0 ? 1ull : 0ull;
            if (co < 64) b0 |= bit << co; else b1 |= bit << (co - 64);
        }
        size_t p = (size_t)n * 1024 + pos;
        A0[p * 2] = b0; A0[p * 2 + 1] = b1;
    }
}

// ---------------------------------------------------------------- weight bit-pack
// Wb layout: [k][cw][co], bit i of word = sign(w[co][cw*64+i][kh][kw]) > 0
__global__ __launch_bounds__(256) void pack_w(const float* __restrict__ w,
                                              u64* __restrict__ Wb, int Ci, int Co) {
    int widx = blockIdx.x * 4 + (threadIdx.x >> 6);
    int lane = threadIdx.x & 63;
    int CW = Ci >> 6;
    int co = widx % Co;
    int rest = widx / Co;
    int cw = rest % CW;
    int k = rest / CW;
    int kh = k / 3, kw = k % 3;
    int ci = (cw << 6) | lane;
    float v = w[((size_t)(co * Ci + ci) * 3 + kh) * 3 + kw];
    u64 m = __ballot(v > 0.0f);
    if (lane == 0) Wb[widx] = m;
}

// ---------------------------------------------------------------- bit binary conv, weights register-cached
// Thread = (n, ho, co), covers the whole output row (WO outputs). Lanes are
// consecutive co -> A loads wave-uniform (broadcast), Wb loads coalesced once.
template <int CW, int CO, int HI, bool POOL>
__global__ __launch_bounds__(256, 2) void bconv_bits2(const u64* __restrict__ A,
                                                      const u64* __restrict__ Wb,
                                                      short* __restrict__ dots) {
    constexpr int WI = HI;
    constexpr int HO = POOL ? HI / 2 : HI;
    constexpr int WO = HO;
    int gid = blockIdx.x * 256 + threadIdx.x;
    int co = gid % CO;
    int rest = gid / CO;
    int ho = rest % HO;
    int n = rest / HO;

    u64 wreg[9 * CW];
    #pragma unroll
    for (int t = 0; t < 9 * CW; ++t) wreg[t] = Wb[(size_t)t * CO + co];

    const u64* An = A + (size_t)n * HI * WI * CW;
    #pragma unroll 2
    for (int wo = 0; wo < WO; ++wo) {
        int best = -(1 << 30);
        #pragma unroll
        for (int py = 0; py < (POOL ? 2 : 1); ++py) {
            #pragma unroll
            for (int px = 0; px < (POOL ? 2 : 1); ++px) {
                int hc = POOL ? 2 * ho + py : ho;
                int wc = POOL ? 2 * wo + px : wo;
                int pc = 0, nv = 0;
                #pragma unroll
                for (int kh = 0; kh < 3; ++kh) {
                    int ih = hc + kh - 1;
                    if ((unsigned)ih >= (unsigned)HI) continue;
                    #pragma unroll
                    for (int kw = 0; kw < 3; ++kw) {
                        int iw = wc + kw - 1;
                        if ((unsigned)iw >= (unsigned)WI) continue;
                        const u64* ap = An + (size_t)(ih * WI + iw) * CW;
                        #pragma unroll
                        for (int cw = 0; cw < CW; ++cw)
                            pc += __popcll(ap[cw] ^ wreg[(kh * 3 + kw) * CW + cw]);
                        nv += CW * 64;
                    }
                }
                int dot = nv - 2 * pc;
                best = dot > best ? dot : best;
            }
        }
        dots[(size_t)((n * HO + ho) * WO + wo) * CO + co] = (short)best;
    }
}

// ---------------------------------------------------------------- BN int stats (exact)
template <int CO>
__global__ void stats_k(const short* __restrict__ xin, int P, i64* __restrict__ sums) {
    int c = threadIdx.x;             // blockDim = CO
    i64 s = 0, s2 = 0;
    for (int p = blockIdx.x; p < P; p += gridDim.x) {
        i64 v = xin[(size_t)p * CO + c];
        s += v;
        s2 += v * v;
    }
    atomicAdd((u64*)&sums[c], (u64)s);
    atomicAdd((u64*)&sums[CO + c], (u64)s2);
}

__global__ void finalize_bn(const i64* __restrict__ sums,
                            const float* __restrict__ g, const float* __restrict__ b,
                            int CO, double cnt, double* __restrict__ M,
                            double* __restrict__ A, double* __restrict__ BB) {
    int c = blockIdx.x * blockDim.x + threadIdx.x;
    if (c >= CO) return;
    double m = (double)sums[c] / cnt;
    double var = (double)sums[CO + c] / cnt - m * m;
    M[c]  = m;
    A[c]  = (double)g[c] / sqrt(var + 1e-5);
    BB[c] = (double)b[c];
}

// ---------------------------------------------------------------- binarize + bit-pack
template <int CO>
__global__ __launch_bounds__(256) void binpack_k(const short* __restrict__ xin,
                                                 const double* __restrict__ M,
                                                 const double* __restrict__ A,
                                                 const double* __restrict__ BB,
                                                 u64* __restrict__ Ab) {
    constexpr int CWo = CO / 64;
    int widx = blockIdx.x * 4 + (threadIdx.x >> 6);
    int lane = threadIdx.x & 63;
    int w = widx & (CWo - 1);
    int p = widx / CWo;
    int c = (w << 6) | lane;
    double t = A[c] * ((double)xin[(size_t)p * CO + c] - M[c]) + BB[c];
    u64 m = __ballot(t > 0.0);
    if (lane == 0) Ab[widx] = m;
}

// ---------------------------------------------------------------- FC head
__global__ __launch_bounds__(256) void fc_k(const short* __restrict__ x5,
                                            const double* __restrict__ M,
                                            const double* __restrict__ A,
                                            const double* __restrict__ BB,
                                            const float* __restrict__ wfc,
                                            const float* __restrict__ bfc,
                                            float* __restrict__ out) {
    int n = blockIdx.x / 10, k = blockIdx.x % 10;
    double acc = 0.0;
    for (int i = threadIdx.x; i < 8192; i += 256) {
        int c = i >> 4, hw = i & 15, h = hw >> 2, ww = hw & 3;
        double t = A[c] * ((double)x5[(size_t)((n * 4 + h) * 4 + ww) * 512 + c] - M[c]) + BB[c];
        t = t < -1.0 ? -1.0 : (t > 1.0 ? 1.0 : t);
        acc += t * (double)wfc[(size_t)k * 8192 + i];
    }
    acc = waveRed(acc);
    __shared__ double sd[4];
    if ((threadIdx.x & 63) == 0) sd[threadIdx.x >> 6] = acc;
    __syncthreads();
    if (threadIdx.x == 0)
        out[n * 10 + k] = (float)(sd[0] + sd[1] + sd[2] + sd[3] + (double)bfc[k]);
}

// ---------------------------------------------------------------- launch
extern "C" void kernel_launch(void* const* d_in, const int* in_sizes, int n_in,
                              void* d_out, int out_size, void* d_ws, size_t ws_size,
                              hipStream_t stream) {
    (void)in_sizes; (void)n_in; (void)out_size; (void)ws_size;

    const float* x   = (const float*)d_in[0];
    const float* w0  = (const float*)d_in[1];
    const float* g0  = (const float*)d_in[2];
    const float* b0  = (const float*)d_in[3];
    const float* w1  = (const float*)d_in[4];
    const float* g1  = (const float*)d_in[5];
    const float* b1  = (const float*)d_in[6];
    const float* w2  = (const float*)d_in[7];
    const float* g2  = (const float*)d_in[8];
    const float* b2  = (const float*)d_in[9];
    const float* w3  = (const float*)d_in[10];
    const float* g3  = (const float*)d_in[11];
    const float* b3  = (const float*)d_in[12];
    const float* w4  = (const float*)d_in[13];
    const float* g4  = (const float*)d_in[14];
    const float* b4  = (const float*)d_in[15];
    const float* w5  = (const float*)d_in[16];
    const float* g5  = (const float*)d_in[17];
    const float* b5  = (const float*)d_in[18];
    const float* wfc = (const float*)d_in[19];
    const float* bfc = (const float*)d_in[20];
    float* out = (float*)d_out;

    // ---- workspace layout (~43.2 MB) ----
    char* ws = (char*)d_ws;
    double* sum0   = (double*)ws;                  // 128
    double* sumsq0 = sum0 + 128;                   // 128
    i64* isums = (i64*)(sumsq0 + 128);             // 5 layers * 1024
    // zero span: 2048 + 40960 = 43008 bytes
    double* M  = (double*)(ws + 65536);            // 6*512
    double* A  = M + 3072;
    double* BB = A + 3072;
    char* p = ws + 65536 + 73728;
    u64* A0 = (u64*)p;  p += (size_t)262144 * 2 * 8;   // 4 MiB
    u64* A1 = (u64*)p;  p += (size_t)65536 * 2 * 8;    // 1 MiB
    u64* A2 = (u64*)p;  p += (size_t)65536 * 4 * 8;    // 2 MiB
    u64* A3 = (u64*)p;  p += (size_t)16384 * 4 * 8;    // 0.5 MiB
    u64* A4 = (u64*)p;  p += (size_t)16384 * 8 * 8;    // 1 MiB
    u64* Wb1 = (u64*)p; p += 2304 * 8;
    u64* Wb2 = (u64*)p; p += 4608 * 8;
    u64* Wb3 = (u64*)p; p += 9216 * 8;
    u64* Wb4 = (u64*)p; p += 18432 * 8;
    u64* Wb5 = (u64*)p; p += 36864 * 8;
    p = (char*)(((uintptr_t)p + 255) & ~(uintptr_t)255);
    short* dots = (short*)p;                       // max 65536*256*2 = 33.5 MB

    hipMemsetAsync(d_ws, 0, 43008, stream);

    // weight bit-packs
    pack_w<<<576,  256, 0, stream>>>(w1, Wb1, 128, 128);
    pack_w<<<1152, 256, 0, stream>>>(w2, Wb2, 128, 256);
    pack_w<<<2304, 256, 0, stream>>>(w3, Wb3, 256, 256);
    pack_w<<<4608, 256, 0, stream>>>(w4, Wb4, 256, 512);
    pack_w<<<9216, 256, 0, stream>>>(w5, Wb5, 512, 512);

    // conv0 (np-f32 FMA (kh,kw,ci)) + BN0 + pack
    conv0_sums2<<<256, 256, 0, stream>>>(x, w0, sum0, sumsq0);
    finalize_c0<<<1, 128, 0, stream>>>(sum0, sumsq0, g0, b0, M, A, BB);
    conv0_pack2<<<256, 256, 0, stream>>>(x, w0, M, A, BB, A0);

    // L1: 128->128 @32x32, pool -> 16x16
    bconv_bits2<2, 128, 32, true><<<2048, 256, 0, stream>>>(A0, Wb1, dots);
    stats_k<128><<<256, 128, 0, stream>>>(dots, 65536, isums);
    finalize_bn<<<1, 128, 0, stream>>>(isums, g1, b1, 128, 65536.0, M + 512, A + 512, BB + 512);
    binpack_k<128><<<32768, 256, 0, stream>>>(dots, M + 512, A + 512, BB + 512, A1);

    // L2: 128->256 @16x16
    bconv_bits2<2, 256, 16, false><<<4096, 256, 0, stream>>>(A1, Wb2, dots);
    stats_k<256><<<256, 256, 0, stream>>>(dots, 65536, isums + 1024);
    finalize_bn<<<1, 256, 0, stream>>>(isums + 1024, g2, b2, 256, 65536.0, M + 1024, A + 1024, BB + 1024);
    binpack_k<256><<<65536, 256, 0, stream>>>(dots, M + 1024, A + 1024, BB + 1024, A2);

    // L3: 256->256 @16x16, pool -> 8x8
    bconv_bits2<4, 256, 16, true><<<2048, 256, 0, stream>>>(A2, Wb3, dots);
    stats_k<256><<<256, 256, 0, stream>>>(dots, 16384, isums + 2048);
    finalize_bn<<<1, 256, 0, stream>>>(isums + 2048, g3, b3, 256, 16384.0, M + 1536, A + 1536, BB + 1536);
    binpack_k<256><<<16384, 256, 0, stream>>>(dots, M + 1536, A + 1536, BB + 1536, A3);

    // L4: 256->512 @8x8
    bconv_bits2<4, 512, 8, false><<<4096, 256, 0, stream>>>(A3, Wb4, dots);
    stats_k<512><<<256, 512, 0, stream>>>(dots, 16384, isums + 3072);
    finalize_bn<<<1, 512, 0, stream>>>(isums + 3072, g4, b4, 512, 16384.0, M + 2048, A + 2048, BB + 2048);
    binpack_k<512><<<32768, 256, 0, stream>>>(dots, M + 2048, A + 2048, BB + 2048, A4);

    // L5: 512->512 @8x8, pool -> 4x4
    bconv_bits2<8, 512, 8, true><<<2048, 256, 0, stream>>>(A4, Wb5, dots);
    stats_k<512><<<256, 512, 0, stream>>>(dots, 4096, isums + 4096);
    finalize_bn<<<1, 512, 0, stream>>>(isums + 4096, g5, b5, 512, 4096.0, M + 2560, A + 2560, BB + 2560);

    // FC head
    fc_k<<<2560, 256, 0, stream>>>(dots, M + 2560, A + 2560, BB + 2560, wfc, bfc, out);
}

// Round 11
// 1189.195 us; speedup vs baseline: 18.4955x; 1.0597x over previous
//
#include <hip/hip_runtime.h>
#include <cstdint>
#include <cstddef>

using u64 = unsigned long long;
using i64 = long long;

#define DEVI __device__ __forceinline__

// ---------------------------------------------------------------- reductions
DEVI double waveRed(double v) {
    #pragma unroll
    for (int o = 32; o > 0; o >>= 1) v += __shfl_down(v, o, 64);
    return v;
}

// ---------------------------------------------------------------- conv0 stats (np-f32: FMA chain, (kh,kw,ci) order)
// One block per image. x + w staged in LDS; weights reordered TAP-MAJOR so
// wsh[co*27 + (kh*3+kw)*3 + ci] pairs with xv[j] (same tap order). Chain runs
// j=0..26 == (kh,kw,ci) order -> bit-identical to the verified R7 arithmetic.
__global__ __launch_bounds__(256, 1) void conv0_sums2(const float* __restrict__ x,
                                                      const float* __restrict__ w0,
                                                      double* __restrict__ sum,
                                                      double* __restrict__ sumsq) {
    __shared__ float xs[3072];
    __shared__ float wsh[3456];
    __shared__ double redS[4][128], redS2[4][128];
    int tid = threadIdx.x, n = blockIdx.x;
    for (int i = tid; i < 3072; i += 256) xs[i] = x[n * 3072 + i];
    for (int i = tid; i < 3456; i += 256) {
        int co = i / 27, j = i % 27;       // j = tap-major (kh*3+kw)*3 + ci
        int ci = j % 3, k = j / 3;
        wsh[i] = w0[co * 27 + ci * 9 + k];
    }
    __syncthreads();

    float xv[4][27];
    #pragma unroll
    for (int k = 0; k < 4; ++k) {
        int pos = tid + k * 256, h = pos >> 5, w = pos & 31;
        #pragma unroll
        for (int kh = 0; kh < 3; ++kh) {
            #pragma unroll
            for (int kw = 0; kw < 3; ++kw) {
                #pragma unroll
                for (int ci = 0; ci < 3; ++ci) {
                    int ih = h + kh - 1, iw = w + kw - 1;
                    bool ok = (unsigned)ih < 32u && (unsigned)iw < 32u;
                    xv[k][(kh * 3 + kw) * 3 + ci] = ok ? xs[ci * 1024 + ih * 32 + iw] : 0.0f;
                }
            }
        }
    }
    int lane = tid & 63, wv = tid >> 6;
    for (int co = 0; co < 128; ++co) {
        #pragma clang fp contract(off)
        const float* wp = &wsh[co * 27];
        float a0 = 0.f, a1 = 0.f, a2 = 0.f, a3 = 0.f;
        #pragma unroll
        for (int j = 0; j < 27; ++j) {
            float wj = wp[j];
            a0 = __builtin_fmaf(xv[0][j], wj, a0);
            a1 = __builtin_fmaf(xv[1][j], wj, a1);
            a2 = __builtin_fmaf(xv[2][j], wj, a2);
            a3 = __builtin_fmaf(xv[3][j], wj, a3);
        }
        double y0 = a0, y1 = a1, y2 = a2, y3 = a3;
        double s  = (y0 + y1) + (y2 + y3);
        double s2 = (y0 * y0 + y1 * y1) + (y2 * y2 + y3 * y3);
        s = waveRed(s); s2 = waveRed(s2);
        if (lane == 0) { redS[wv][co] = s; redS2[wv][co] = s2; }
    }
    __syncthreads();
    if (tid < 128) {
        atomicAdd(&sum[tid], (redS[0][tid] + redS[1][tid]) + (redS[2][tid] + redS[3][tid]));
    } else {
        int c = tid - 128;
        atomicAdd(&sumsq[c], (redS2[0][c] + redS2[1][c]) + (redS2[2][c] + redS2[3][c]));
    }
}

__global__ void finalize_c0(const double* __restrict__ sum, const double* __restrict__ sumsq,
                            const float* __restrict__ g, const float* __restrict__ b,
                            double* __restrict__ M, double* __restrict__ A,
                            double* __restrict__ BB) {
    int c = threadIdx.x;    // 128
    double m = sum[c] / 262144.0;
    double var = sumsq[c] / 262144.0 - m * m;
    M[c]  = m;
    A[c]  = (double)g[c] / sqrt(var + 1e-5);
    BB[c] = (double)b[c];
}

// ---------------------------------------------------------------- conv0 pack
__global__ __launch_bounds__(256, 1) void conv0_pack2(const float* __restrict__ x,
                                                      const float* __restrict__ w0,
                                                      const double* __restrict__ M,
                                                      const double* __restrict__ A,
                                                      const double* __restrict__ BB,
                                                      u64* __restrict__ A0) {
    __shared__ float xs[3072];
    __shared__ float wsh[3456];
    __shared__ double msh[128], ash[128], bsh[128];
    int tid = threadIdx.x, n = blockIdx.x;
    for (int i = tid; i < 3072; i += 256) xs[i] = x[n * 3072 + i];
    for (int i = tid; i < 3456; i += 256) {
        int co = i / 27, j = i % 27;       // j = tap-major (kh*3+kw)*3 + ci
        int ci = j % 3, k = j / 3;
        wsh[i] = w0[co * 27 + ci * 9 + k];
    }
    if (tid < 128) { msh[tid] = M[tid]; ash[tid] = A[tid]; bsh[tid] = BB[tid]; }
    __syncthreads();

    for (int k = 0; k < 4; ++k) {
        int pos = tid + k * 256, h = pos >> 5, w = pos & 31;
        float xv[27];
        #pragma unroll
        for (int kh = 0; kh < 3; ++kh) {
            #pragma unroll
            for (int kw = 0; kw < 3; ++kw) {
                #pragma unroll
                for (int ci = 0; ci < 3; ++ci) {
                    int ih = h + kh - 1, iw = w + kw - 1;
                    bool ok = (unsigned)ih < 32u && (unsigned)iw < 32u;
                    xv[(kh * 3 + kw) * 3 + ci] = ok ? xs[ci * 1024 + ih * 32 + iw] : 0.0f;
                }
            }
        }
        u64 b0 = 0, b1 = 0;
        #pragma unroll 4
        for (int co = 0; co < 128; ++co) {
            #pragma clang fp contract(off)
            float acc = 0.f;
            const float* wp = &wsh[co * 27];
            #pragma unroll
            for (int j = 0; j < 27; ++j) acc = __builtin_fmaf(xv[j], wp[j], acc);
            double t = ash[co] * ((double)acc - msh[co]) + bsh[co];
            u64 bit = t > 0.0 ? 1ull : 0ull;
            if (co < 64) b0 |= bit << co; else b1 |= bit << (co - 64);
        }
        size_t p = (size_t)n * 1024 + pos;
        A0[p * 2] = b0; A0[p * 2 + 1] = b1;
    }
}

// ---------------------------------------------------------------- weight bit-pack
__global__ __launch_bounds__(256) void pack_w(const float* __restrict__ w,
                                              u64* __restrict__ Wb, int Ci, int Co) {
    int widx = blockIdx.x * 4 + (threadIdx.x >> 6);
    int lane = threadIdx.x & 63;
    int CW = Ci >> 6;
    int co = widx % Co;
    int rest = widx / Co;
    int cw = rest % CW;
    int k = rest / CW;
    int kh = k / 3, kw = k % 3;
    int ci = (cw << 6) | lane;
    float v = w[((size_t)(co * Ci + ci) * 3 + kh) * 3 + kw];
    u64 m = __ballot(v > 0.0f);
    if (lane == 0) Wb[widx] = m;
}

// ---------------------------------------------------------------- bit binary conv + fused BN stats
// Thread = (n, ho, co); covers the full output row. Weights in registers,
// A-taps via 16B vector loads (CW even -> aligned). Epilogue: per-thread
// int32 sum/sumsq accumulated, two i64 global atomics (two's complement).
template <int CW, int CO, int HI, bool POOL>
__global__ __launch_bounds__(256, 2) void bconv_bits3(const u64* __restrict__ A,
                                                      const u64* __restrict__ Wb,
                                                      short* __restrict__ dots,
                                                      i64* __restrict__ sums) {
    constexpr int WI = HI;
    constexpr int HO = POOL ? HI / 2 : HI;
    constexpr int WO = HO;
    int gid = blockIdx.x * 256 + threadIdx.x;
    int co = gid % CO;
    int rest = gid / CO;
    int ho = rest % HO;
    int n = rest / HO;

    u64 wreg[9 * CW];
    #pragma unroll
    for (int t = 0; t < 9 * CW; ++t) wreg[t] = Wb[(size_t)t * CO + co];

    const u64* An = A + (size_t)n * HI * WI * CW;
    int s = 0, s2 = 0;
    #pragma unroll 2
    for (int wo = 0; wo < WO; ++wo) {
        int best = -(1 << 30);
        #pragma unroll
        for (int py = 0; py < (POOL ? 2 : 1); ++py) {
            #pragma unroll
            for (int px = 0; px < (POOL ? 2 : 1); ++px) {
                int hc = POOL ? 2 * ho + py : ho;
                int wc = POOL ? 2 * wo + px : wo;
                int pc = 0, nv = 0;
                #pragma unroll
                for (int kh = 0; kh < 3; ++kh) {
                    int ih = hc + kh - 1;
                    if ((unsigned)ih >= (unsigned)HI) continue;
                    #pragma unroll
                    for (int kw = 0; kw < 3; ++kw) {
                        int iw = wc + kw - 1;
                        if ((unsigned)iw >= (unsigned)WI) continue;
                        const ulonglong2* ap =
                            (const ulonglong2*)(An + (size_t)(ih * WI + iw) * CW);
                        #pragma unroll
                        for (int cw = 0; cw < CW / 2; ++cw) {
                            ulonglong2 v = ap[cw];
                            pc += __popcll(v.x ^ wreg[(kh * 3 + kw) * CW + 2 * cw])
                                + __popcll(v.y ^ wreg[(kh * 3 + kw) * CW + 2 * cw + 1]);
                        }
                        nv += CW * 64;
                    }
                }
                int dot = nv - 2 * pc;
                best = dot > best ? dot : best;
            }
        }
        dots[(size_t)((n * HO + ho) * WO + wo) * CO + co] = (short)best;
        s += best;
        s2 += best * best;
    }
    atomicAdd((u64*)&sums[co], (u64)(i64)s);
    atomicAdd((u64*)&sums[CO + co], (u64)(i64)s2);
}

__global__ void finalize_bn(const i64* __restrict__ sums,
                            const float* __restrict__ g, const float* __restrict__ b,
                            int CO, double cnt, double* __restrict__ M,
                            double* __restrict__ A, double* __restrict__ BB) {
    int c = blockIdx.x * blockDim.x + threadIdx.x;
    if (c >= CO) return;
    double m = (double)sums[c] / cnt;
    double var = (double)sums[CO + c] / cnt - m * m;
    M[c]  = m;
    A[c]  = (double)g[c] / sqrt(var + 1e-5);
    BB[c] = (double)b[c];
}

// ---------------------------------------------------------------- binarize + bit-pack
template <int CO>
__global__ __launch_bounds__(256) void binpack_k(const short* __restrict__ xin,
                                                 const double* __restrict__ M,
                                                 const double* __restrict__ A,
                                                 const double* __restrict__ BB,
                                                 u64* __restrict__ Ab) {
    constexpr int CWo = CO / 64;
    int widx = blockIdx.x * 4 + (threadIdx.x >> 6);
    int lane = threadIdx.x & 63;
    int w = widx & (CWo - 1);
    int p = widx / CWo;
    int c = (w << 6) | lane;
    double t = A[c] * ((double)xin[(size_t)p * CO + c] - M[c]) + BB[c];
    u64 m = __ballot(t > 0.0);
    if (lane == 0) Ab[widx] = m;
}

// ---------------------------------------------------------------- FC head
__global__ __launch_bounds__(256) void fc_k(const short* __restrict__ x5,
                                            const double* __restrict__ M,
                                            const double* __restrict__ A,
                                            const double* __restrict__ BB,
                                            const float* __restrict__ wfc,
                                            const float* __restrict__ bfc,
                                            float* __restrict__ out) {
    int n = blockIdx.x / 10, k = blockIdx.x % 10;
    double acc = 0.0;
    for (int i = threadIdx.x; i < 8192; i += 256) {
        int c = i >> 4, hw = i & 15, h = hw >> 2, ww = hw & 3;
        double t = A[c] * ((double)x5[(size_t)((n * 4 + h) * 4 + ww) * 512 + c] - M[c]) + BB[c];
        t = t < -1.0 ? -1.0 : (t > 1.0 ? 1.0 : t);
        acc += t * (double)wfc[(size_t)k * 8192 + i];
    }
    acc = waveRed(acc);
    __shared__ double sd[4];
    if ((threadIdx.x & 63) == 0) sd[threadIdx.x >> 6] = acc;
    __syncthreads();
    if (threadIdx.x == 0)
        out[n * 10 + k] = (float)(sd[0] + sd[1] + sd[2] + sd[3] + (double)bfc[k]);
}

// ---------------------------------------------------------------- launch
extern "C" void kernel_launch(void* const* d_in, const int* in_sizes, int n_in,
                              void* d_out, int out_size, void* d_ws, size_t ws_size,
                              hipStream_t stream) {
    (void)in_sizes; (void)n_in; (void)out_size; (void)ws_size;

    const float* x   = (const float*)d_in[0];
    const float* w0  = (const float*)d_in[1];
    const float* g0  = (const float*)d_in[2];
    const float* b0  = (const float*)d_in[3];
    const float* w1  = (const float*)d_in[4];
    const float* g1  = (const float*)d_in[5];
    const float* b1  = (const float*)d_in[6];
    const float* w2  = (const float*)d_in[7];
    const float* g2  = (const float*)d_in[8];
    const float* b2  = (const float*)d_in[9];
    const float* w3  = (const float*)d_in[10];
    const float* g3  = (const float*)d_in[11];
    const float* b3  = (const float*)d_in[12];
    const float* w4  = (const float*)d_in[13];
    const float* g4  = (const float*)d_in[14];
    const float* b4  = (const float*)d_in[15];
    const float* w5  = (const float*)d_in[16];
    const float* g5  = (const float*)d_in[17];
    const float* b5  = (const float*)d_in[18];
    const float* wfc = (const float*)d_in[19];
    const float* bfc = (const float*)d_in[20];
    float* out = (float*)d_out;

    // ---- workspace layout (~43.2 MB) ----
    char* ws = (char*)d_ws;
    double* sum0   = (double*)ws;                  // 128
    double* sumsq0 = sum0 + 128;                   // 128
    i64* isums = (i64*)(sumsq0 + 128);             // 5 layers * 1024
    // zero span: 2048 + 40960 = 43008 bytes
    double* M  = (double*)(ws + 65536);            // 6*512
    double* A  = M + 3072;
    double* BB = A + 3072;
    char* p = ws + 65536 + 73728;
    u64* A0 = (u64*)p;  p += (size_t)262144 * 2 * 8;   // 4 MiB
    u64* A1 = (u64*)p;  p += (size_t)65536 * 2 * 8;    // 1 MiB
    u64* A2 = (u64*)p;  p += (size_t)65536 * 4 * 8;    // 2 MiB
    u64* A3 = (u64*)p;  p += (size_t)16384 * 4 * 8;    // 0.5 MiB
    u64* A4 = (u64*)p;  p += (size_t)16384 * 8 * 8;    // 1 MiB
    u64* Wb1 = (u64*)p; p += 2304 * 8;
    u64* Wb2 = (u64*)p; p += 4608 * 8;
    u64* Wb3 = (u64*)p; p += 9216 * 8;
    u64* Wb4 = (u64*)p; p += 18432 * 8;
    u64* Wb5 = (u64*)p; p += 36864 * 8;
    p = (char*)(((uintptr_t)p + 255) & ~(uintptr_t)255);
    short* dots = (short*)p;                       // max 65536*256*2 = 33.5 MB

    hipMemsetAsync(d_ws, 0, 43008, stream);

    // weight bit-packs
    pack_w<<<576,  256, 0, stream>>>(w1, Wb1, 128, 128);
    pack_w<<<1152, 256, 0, stream>>>(w2, Wb2, 128, 256);
    pack_w<<<2304, 256, 0, stream>>>(w3, Wb3, 256, 256);
    pack_w<<<4608, 256, 0, stream>>>(w4, Wb4, 256, 512);
    pack_w<<<9216, 256, 0, stream>>>(w5, Wb5, 512, 512);

    // conv0 (np-f32 FMA (kh,kw,ci)) + BN0 + pack
    conv0_sums2<<<256, 256, 0, stream>>>(x, w0, sum0, sumsq0);
    finalize_c0<<<1, 128, 0, stream>>>(sum0, sumsq0, g0, b0, M, A, BB);
    conv0_pack2<<<256, 256, 0, stream>>>(x, w0, M, A, BB, A0);

    // L1: 128->128 @32x32, pool -> 16x16
    bconv_bits3<2, 128, 32, true><<<2048, 256, 0, stream>>>(A0, Wb1, dots, isums);
    finalize_bn<<<1, 128, 0, stream>>>(isums, g1, b1, 128, 65536.0, M + 512, A + 512, BB + 512);
    binpack_k<128><<<32768, 256, 0, stream>>>(dots, M + 512, A + 512, BB + 512, A1);

    // L2: 128->256 @16x16
    bconv_bits3<2, 256, 16, false><<<4096, 256, 0, stream>>>(A1, Wb2, dots, isums + 1024);
    finalize_bn<<<1, 256, 0, stream>>>(isums + 1024, g2, b2, 256, 65536.0, M + 1024, A + 1024, BB + 1024);
    binpack_k<256><<<65536, 256, 0, stream>>>(dots, M + 1024, A + 1024, BB + 1024, A2);

    // L3: 256->256 @16x16, pool -> 8x8
    bconv_bits3<4, 256, 16, true><<<2048, 256, 0, stream>>>(A2, Wb3, dots, isums + 2048);
    finalize_bn<<<1, 256, 0, stream>>>(isums + 2048, g3, b3, 256, 16384.0, M + 1536, A + 1536, BB + 1536);
    binpack_k<256><<<16384, 256, 0, stream>>>(dots, M + 1536, A + 1536, BB + 1536, A3);

    // L4: 256->512 @8x8
    bconv_bits3<4, 512, 8, false><<<4096, 256, 0, stream>>>(A3, Wb4, dots, isums + 3072);
    finalize_bn<<<1, 512, 0, stream>>>(isums + 3072, g4, b4, 512, 16384.0, M + 2048, A + 2048, BB + 2048);
    binpack_k<512><<<32768, 256, 0, stream>>>(dots, M + 2048, A + 2048, BB + 2048, A4);

    // L5: 512->512 @8x8, pool -> 4x4
    bconv_bits3<8, 512, 8, true><<<2048, 256, 0, stream>>>(A4, Wb5, dots, isums + 4096);
    finalize_bn<<<1, 512, 0, stream>>>(isums + 4096, g5, b5, 512, 4096.0, M + 2560, A + 2560, BB + 2560);

    // FC head
    fc_k<<<2560, 256, 0, stream>>>(dots, M + 2560, A + 2560, BB + 2560, wfc, bfc, out);
}